// Round 9
// baseline (397.140 us; speedup 1.0000x reference)
//
#include <hip/hip_runtime.h>
#include <math.h>

// Problem constants
#define B_   4096
#define T_   193
#define D_   50
#define H_   50
#define V_   11
#define BT   8                     // batch rows per block (8 of 16 MFMA cols real)
#define NBLK (B_ / BT)             // 512 blocks -> 2 blocks/CU: two independent
                                   // 13-wave barrier convoys per CU (phase diversity)
#define CH   16                    // timesteps per LDS chunk (double-buffered)
#define NCH  ((T_ + CH - 1) / CH)  // 13 chunks (12x16 + 1)
#define NTHREADS 832               // 13 waves, ALL active (one gate-tile each)
#define NP   ((CH * 128 + NTHREADS - 1) / NTHREADS)   // 3 staging frags/thread

typedef __bf16 bf16x8 __attribute__((ext_vector_type(8)));
typedef float  f32x4  __attribute__((ext_vector_type(4)));

__device__ __forceinline__ float sigf(float v) { return 1.0f / (1.0f + __expf(-v)); }
__device__ __forceinline__ float thf(float v)  { return 2.0f / (1.0f + __expf(-2.0f * v)) - 1.0f; }

// LDS-only barrier: leaves global loads in flight (unlike __syncthreads'
// vmcnt(0) drain) so the async next-chunk x prefetch survives step barriers.
__device__ __forceinline__ void lgkm_barrier() {
    asm volatile("s_waitcnt lgkmcnt(0)\n\ts_barrier" ::: "memory");
}

// Per-step GEMM  gates^T[208,16] = Wcat'[208,128] @ act^T[128,16] via
// mfma_f32_16x16x32_bf16, fp32 accum. Gate interleave g' = 4*j + q puts
// {i,f,g,o} of hidden unit j in one lane's 4 acc regs (lane-local cell update).
// K layout: [0,50) x_t; [50,64) pad; [64,114) h; [114,127) pad; 127 = bias.
//
// R8 vs R7: BT 16->8 with the SAME 13-wave/1-tile-per-wave structure and
// CH=16 (LDS ~72KB) so TWO blocks co-reside per CU. R7's books: measured
// 2240 cyc/step vs <700 cyc of pipe work -> barrier-convoy bound. Two
// independent convoys give each SIMD ~6.5 waves in two unsynchronized
// phase groups; one convoy's barrier stall overlaps the other's compute.
// (R5 tested 2 blocks with 3-4 tiles/wave -- confounded; this isolates it.)
// Pad batch cols n>=8 mirror rows 0..7 (bounded values, L1-hot, results unused).
__global__ __launch_bounds__(NTHREADS, 7) void lstm_mfma_kernel(
    const float* __restrict__ x,      // [B, T, D]
    const float* __restrict__ W_ih,   // [200, 50]
    const float* __restrict__ W_hh,   // [200, 50]
    const float* __restrict__ b_ih,   // [200]
    const float* __restrict__ b_hh,   // [200]
    const float* __restrict__ fc_w,   // [11, 50]
    const float* __restrict__ fc_b,   // [11]
    float* __restrict__ out)          // [B, 11]
{
    // xs: 2 chunk buffers of [tc][s][lane][8 bf16] fragments. 2 x 32 KB
    __shared__ __align__(16) unsigned short xs[2 * CH * 2 * 64 * 8];
    // hb: double-buffered h B-fragments + bias slot. 4 KB
    __shared__ __align__(16) unsigned short hb[2 * 2 * 64 * 8];
    __shared__ float hfin[BT * 53];
    __shared__ float lgts[BT][V_];

    const int tid  = threadIdx.x;
    const int wid  = tid >> 6;
    const int lane = tid & 63;
    const int n    = lane & 15;   // A-row within tile / B batch col
    const int kg   = lane >> 4;   // k-group
    const int row0 = blockIdx.x * BT;
    const int tile = wid;         // one 16-row gate tile per wave (0..12)

    // ---- init hb: zeros + bias slot (u=63 -> bf16 1.0) in both buffers ----
    if (tid < 256) {
        int4 z; z.x = 0; z.y = 0; z.z = 0; z.w = 0;
        reinterpret_cast<int4*>(hb)[tid] = z;   // 256*16B = 4096B
    }
    if (tid < 32) {
        hb[((tid >> 4) * 2 + 1) * 512 + (48 + (tid & 15)) * 8 + 7] = 0x3F80;
    }

    // ---- this wave's weight A-fragments (4 ksteps) ----
    bf16x8 wf[4];
    {
        #pragma unroll
        for (int s = 0; s < 4; ++s) {
            float tv[8];
            #pragma unroll
            for (int j = 0; j < 8; ++j) tv[j] = 0.0f;
            const int gp = 16 * tile + n;  // g' (A-row this lane holds)
            const int q  = gp & 3;
            const int ju = gp >> 2;
            if (ju < 50) {
                const int row = q * 50 + ju;
                #pragma unroll
                for (int j = 0; j < 8; ++j) {
                    const int k = s * 32 + kg * 8 + j;
                    float v = 0.0f;
                    if (k < 50)                  v = W_ih[row * 50 + k];
                    else if (k >= 64 && k < 114) v = W_hh[row * 50 + (k - 64)];
                    else if (k == 127)           v = b_ih[row] + b_hh[row];
                    tv[j] = v;
                }
            }
            bf16x8 w;
            #pragma unroll
            for (int j = 0; j < 8; ++j) w[j] = (__bf16)tv[j];
            wf[s] = w;
        }
    }

    // h LDS write offset (ushort index within one hb buffer); u = hidden unit
    const int u_   = 4 * tile + kg;
    const int hoff = (u_ >> 5) * 512 + ((((u_ & 31) >> 3) << 4) | n) * 8 + (u_ & 7);

    // ---- chunk staging: global->regs (async) then regs->LDS bf16 frags ----
    float2 P[NP][4];   // 24 VGPRs; static indexing only (full unroll)

    auto loadChunk = [&](int c) {
        const int t0 = c * CH;
        const int L  = (T_ - t0 < CH) ? (T_ - t0) : CH;
        const int nfrag = L * 128;
        #pragma unroll
        for (int i = 0; i < NP; ++i) {
            const int fi = tid + i * NTHREADS;
            if (fi < nfrag) {
                const int tc  = fi >> 7;
                const int rem = fi & 127;
                const int s   = rem >> 6;
                const int l   = rem & 63;
                const int nn  = (l & 15) & (BT - 1);  // pad cols mirror rows 0..7
                const int kk  = l >> 4;
                const float* base = x + ((size_t)(row0 + nn) * T_ + (t0 + tc)) * D_;
                #pragma unroll
                for (int j = 0; j < 4; ++j) {
                    int col = 32 * s + kk * 8 + 2 * j;
                    if (col > 48) col = 48;   // clamp: finite garbage * 0-weight
                    P[i][j] = *reinterpret_cast<const float2*>(base + col);
                }
            }
        }
    };
    auto writeChunk = [&](int c, int b) {
        const int t0 = c * CH;
        const int L  = (T_ - t0 < CH) ? (T_ - t0) : CH;
        const int nfrag = L * 128;
        #pragma unroll
        for (int i = 0; i < NP; ++i) {
            const int fi = tid + i * NTHREADS;
            if (fi < nfrag) {
                bf16x8 w;
                #pragma unroll
                for (int j = 0; j < 4; ++j) {
                    w[2 * j]     = (__bf16)P[i][j].x;
                    w[2 * j + 1] = (__bf16)P[i][j].y;
                }
                reinterpret_cast<int4*>(xs)[b * (CH * 128) + fi] =
                    __builtin_bit_cast(int4, w);
            }
        }
    };

    loadChunk(0);
    writeChunk(0, 0);
    __syncthreads();        // one full (vmcnt) drain for chunk 0
    loadChunk(1);           // chunk 1 flies during chunk 0's 16 steps

    float cst = 0.0f;
    float hlast = 0.0f;
    int cur = 0;
    const int4* xsv = reinterpret_cast<const int4*>(xs);

    for (int c = 0; c < NCH; ++c) {
        const int t0 = c * CH;
        const int L  = (T_ - t0 < CH) ? (T_ - t0) : CH;
        const int b  = c & 1;

        // x-projection for step 0 of this chunk (buffer valid post-barrier)
        f32x4 ax;
        {
            const bf16x8 bx0 = __builtin_bit_cast(bf16x8, xsv[b * (CH * 128) + lane]);
            const bf16x8 bx1 = __builtin_bit_cast(bf16x8, xsv[b * (CH * 128) + 64 + lane]);
            f32x4 z = {0.0f, 0.0f, 0.0f, 0.0f};
            z  = __builtin_amdgcn_mfma_f32_16x16x32_bf16(wf[0], bx0, z, 0, 0, 0);
            ax = __builtin_amdgcn_mfma_f32_16x16x32_bf16(wf[1], bx1, z, 0, 0, 0);
        }

        for (int tc = 0; tc < L; ++tc) {
            // ---- post-barrier critical path: h reads -> 2 MFMA -> act ----
            const int4* hbv = reinterpret_cast<const int4*>(hb) + cur * 128;
            const bf16x8 bh0 = __builtin_bit_cast(bf16x8, hbv[lane]);
            const bf16x8 bh1 = __builtin_bit_cast(bf16x8, hbv[64 + lane]);
            f32x4 a = __builtin_amdgcn_mfma_f32_16x16x32_bf16(wf[2], bh0, ax, 0, 0, 0);
            a = __builtin_amdgcn_mfma_f32_16x16x32_bf16(wf[3], bh1, a, 0, 0, 0);

            const float ii = sigf(a[0]);
            const float ff = sigf(a[1]);
            const float g2 = thf(a[2]);
            const float oo = sigf(a[3]);
            cst = ff * cst + ii * g2;
            const float h = oo * thf(cst);
            hlast = h;
            hb[(cur ^ 1) * 1024 + hoff] =
                __builtin_bit_cast(unsigned short, (__bf16)h);

            // ---- pre-barrier slack: next step's x projection ----
            if (tc + 1 < L) {
                const bf16x8 nx0 = __builtin_bit_cast(
                    bf16x8, xsv[b * (CH * 128) + (tc + 1) * 128 + lane]);
                const bf16x8 nx1 = __builtin_bit_cast(
                    bf16x8, xsv[b * (CH * 128) + (tc + 1) * 128 + 64 + lane]);
                f32x4 z = {0.0f, 0.0f, 0.0f, 0.0f};
                z  = __builtin_amdgcn_mfma_f32_16x16x32_bf16(wf[0], nx0, z, 0, 0, 0);
                ax = __builtin_amdgcn_mfma_f32_16x16x32_bf16(wf[1], nx1, z, 0, 0, 0);
            }

            if (tc == L - 1) {
                if (c + 1 < NCH) writeChunk(c + 1, b ^ 1);  // vmcnt auto-waited
                if (c + 2 < NCH) loadChunk(c + 2);          // next prefetch flies
            }

            lgkm_barrier();   // LDS-only sync; global prefetch stays in flight
            cur ^= 1;
        }
    }

    // final h -> LDS (real batch cols only)
    if (n < BT) hfin[n * 53 + u_] = hlast;
    __syncthreads();

    // ---- FC head + log_softmax ----
    if (tid < BT * V_) {
        const int bn = tid / V_;
        const int v  = tid % V_;
        float a = fc_b[v];
        #pragma unroll
        for (int j = 0; j < 50; ++j) {
            float hj = hfin[bn * 53 + j];
            hj = hj > 0.0f ? hj : 0.0f;
            a = fmaf(hj, fc_w[v * 50 + j], a);
        }
        lgts[bn][v] = a;
    }
    __syncthreads();
    if (tid < BT * V_) {
        const int bn = tid / V_;
        const int v  = tid % V_;
        float m = -1e30f;
        #pragma unroll
        for (int u = 0; u < V_; ++u) m = fmaxf(m, lgts[bn][u]);
        float s = 0.0f;
        #pragma unroll
        for (int u = 0; u < V_; ++u) s += __expf(lgts[bn][u] - m);
        out[(size_t)(row0 + bn) * V_ + v] = lgts[bn][v] - m - __logf(s);
    }
}

extern "C" void kernel_launch(void* const* d_in, const int* in_sizes, int n_in,
                              void* d_out, int out_size, void* d_ws, size_t ws_size,
                              hipStream_t stream) {
    const float* x    = (const float*)d_in[0];
    const float* W_ih = (const float*)d_in[1];
    const float* W_hh = (const float*)d_in[2];
    const float* b_ih = (const float*)d_in[3];
    const float* b_hh = (const float*)d_in[4];
    const float* fc_w = (const float*)d_in[5];
    const float* fc_b = (const float*)d_in[6];
    float* out = (float*)d_out;

    lstm_mfma_kernel<<<NBLK, NTHREADS, 0, stream>>>(
        x, W_ih, W_hh, b_ih, b_hh, fc_w, fc_b, out);
}

// Round 12
// 214.292 us; speedup vs baseline: 1.8533x; 1.8533x over previous
//
#include <hip/hip_runtime.h>
#include <math.h>

// Problem constants
#define B_   4096
#define T_   193
#define D_   50
#define H_   50
#define V_   11
#define BT   16                    // batch rows per block
#define NBLK (B_ / BT)             // 256 blocks = 1 block/CU
#define CH   16                    // timesteps per LDS chunk (double-buffered)
#define NCH  ((T_ + CH - 1) / CH)  // 13 chunks (12 full + L=1 tail)
#define NTHREADS 448               // 7 waves, 2 gate-tiles per wave
#define NP   5                     // staging frags/thread (448*5 >= 16*128)

typedef __bf16 bf16x8 __attribute__((ext_vector_type(8)));
typedef float  f32x4  __attribute__((ext_vector_type(4)));

__device__ __forceinline__ float sigf(float v) { return 1.0f / (1.0f + __expf(-v)); }
__device__ __forceinline__ float thf(float v)  { return 2.0f / (1.0f + __expf(-2.0f * v)) - 1.0f; }

// LDS-only barrier: leaves global loads in flight (unlike __syncthreads'
// vmcnt(0) drain) so the async next-chunk x prefetch survives step barriers.
__device__ __forceinline__ void lgkm_barrier() {
    asm volatile("s_waitcnt lgkmcnt(0)\n\ts_barrier" ::: "memory");
}

// R11 = R10 precision-hardened design + two init-bug fixes:
//   BUG 1 (the R10 failure): hb grew to 8KB (512 int4) but zero-init still
//     covered only 256 int4 -> buf 1's h_lo bias column (k=63) kept STALE
//     LDS from the previous dispatch; whh_hi[k=63]=bf16(bias) != 0
//     multiplied garbage into every odd step's gates (absmax 0.1875).
//     Fix: zero ALL 512 int4.
//   BUG 2 (latent since R4): the bias-slot write raced the zero-init of the
//     same int4 done by a different wave. Fix: __syncthreads() between.
// Precision design (unchanged from R10): W = W_hi + W_lo bf16 split;
// h state stored hi+lo; W*h ~= Whh_hi*h_hi + Whh_hi*h_lo + Whh_lo*h_hi;
// bias rides k=63 of the h-part vs the constant-1.0 B slot (hi+lo exact).
// Only remaining quantization source: x -> bf16.
__global__ __launch_bounds__(NTHREADS, 2) void lstm_mfma_kernel(
    const float* __restrict__ x,      // [B, T, D]
    const float* __restrict__ W_ih,   // [200, 50]
    const float* __restrict__ W_hh,   // [200, 50]
    const float* __restrict__ b_ih,   // [200]
    const float* __restrict__ b_hh,   // [200]
    const float* __restrict__ fc_w,   // [11, 50]
    const float* __restrict__ fc_b,   // [11]
    float* __restrict__ out)          // [B, 11]
{
    // xs: 2 chunk buffers of [tc][s][lane][8 bf16] fragments. 2 x 32 KB
    __shared__ __align__(16) unsigned short xs[2 * CH * 2 * 64 * 8];
    // hb: 2 bufs x 4 sets (h_hi k0,k1 | h_lo k0,k1) x [64][8]. 8 KB
    __shared__ __align__(16) unsigned short hb[2 * 4 * 64 * 8];
    __shared__ float hfin[BT * 53];
    __shared__ float lgts[BT][V_];

    const int tid  = threadIdx.x;
    const int wid  = tid >> 6;
    const int lane = tid & 63;
    const int n    = lane & 15;   // A-row within tile / B batch col
    const int kg   = lane >> 4;   // k-group
    const int row0 = blockIdx.x * BT;
    const int tA   = 2 * wid;     // gate tiles (13 = dummy, zero weights)
    const int tB   = 2 * wid + 1;

    // ---- init hb: zero ALL 512 int4 (both bufs, hi+lo sets)  [BUG-1 fix] ----
    {
        int4 z; z.x = 0; z.y = 0; z.z = 0; z.w = 0;
        #pragma unroll
        for (int i = tid; i < 512; i += NTHREADS)
            reinterpret_cast<int4*>(hb)[i] = z;
    }
    __syncthreads();   // [BUG-2 fix] bias write must not race the zeroing
    if (tid < 32) {
        // bias slot u=63 (h_hi, set 1, lane 48+n, j=7) of buf (tid>>4)
        hb[(tid >> 4) * 2048 + 512 + (48 + (tid & 15)) * 8 + 7] = 0x3F80;
    }

    // ---- weight fragments, hi+lo, both tiles ----
    // x-part ksteps 0,1 (k in [0,64)): W_ih cols; h-part ksteps 0,1: W_hh
    // cols (k<50), bias at k=63.
    bf16x8 wxhA[2], wxlA[2], whhA[2], whlA[2];
    bf16x8 wxhB[2], wxlB[2], whhB[2], whlB[2];
    #pragma unroll
    for (int ti = 0; ti < 2; ++ti) {
        const int gp = 16 * (ti == 0 ? tA : tB) + n;  // g'
        const int q  = gp & 3;
        const int ju = gp >> 2;
        const bool real = (ju < 50);
        const int row = real ? (q * 50 + ju) : 0;
        #pragma unroll
        for (int s = 0; s < 2; ++s) {
            bf16x8 xh, xl, hh, hl;
            #pragma unroll
            for (int j = 0; j < 8; ++j) {
                const int k = s * 32 + kg * 8 + j;
                float vx = 0.0f, vh = 0.0f;
                if (real) {
                    if (k < 50) { vx = W_ih[row * 50 + k]; vh = W_hh[row * 50 + k]; }
                    if (k == 63) vh = b_ih[row] + b_hh[row];
                }
                const __bf16 xhi = (__bf16)vx;
                const __bf16 hhi = (__bf16)vh;
                xh[j] = xhi; xl[j] = (__bf16)(vx - (float)xhi);
                hh[j] = hhi; hl[j] = (__bf16)(vh - (float)hhi);
            }
            if (ti == 0) { wxhA[s] = xh; wxlA[s] = xl; whhA[s] = hh; whlA[s] = hl; }
            else         { wxhB[s] = xh; wxlB[s] = xl; whhB[s] = hh; whlB[s] = hl; }
        }
    }

    // h LDS write offsets within the hi region (lo = +1024)
    const int uA = 4 * tA + kg;
    const int uB = 4 * tB + kg;
    const int hoffA = (uA >> 5) * 512 + ((((uA & 31) >> 3) << 4) | n) * 8 + (uA & 7);
    const int hoffB = (uB >> 5) * 512 + ((((uB & 31) >> 3) << 4) | n) * 8 + (uB & 7);

    // ---- chunk staging: global->regs (async) then regs->LDS bf16 frags ----
    float2 P[NP][4];   // 40 VGPRs; static indexing only (full unroll)

    auto loadChunk = [&](int c) {
        const int t0 = c * CH;
        const int L  = (T_ - t0 < CH) ? (T_ - t0) : CH;
        const int nfrag = L * 128;
        #pragma unroll
        for (int i = 0; i < NP; ++i) {
            const int fi = tid + i * NTHREADS;
            if (fi < nfrag) {
                const int tc  = fi >> 7;
                const int rem = fi & 127;
                const int s   = rem >> 6;
                const int l   = rem & 63;
                const int nn  = l & 15;
                const int kk  = l >> 4;
                const float* base = x + ((size_t)(row0 + nn) * T_ + (t0 + tc)) * D_;
                #pragma unroll
                for (int j = 0; j < 4; ++j) {
                    int col = 32 * s + kk * 8 + 2 * j;
                    if (col > 48) col = 48;   // clamp: finite garbage * 0-weight
                    P[i][j] = *reinterpret_cast<const float2*>(base + col);
                }
            }
        }
    };
    auto writeChunk = [&](int c, int b) {
        const int t0 = c * CH;
        const int L  = (T_ - t0 < CH) ? (T_ - t0) : CH;
        const int nfrag = L * 128;
        #pragma unroll
        for (int i = 0; i < NP; ++i) {
            const int fi = tid + i * NTHREADS;
            if (fi < nfrag) {
                bf16x8 w;
                #pragma unroll
                for (int j = 0; j < 4; ++j) {
                    w[2 * j]     = (__bf16)P[i][j].x;
                    w[2 * j + 1] = (__bf16)P[i][j].y;
                }
                reinterpret_cast<int4*>(xs)[b * (CH * 128) + fi] =
                    __builtin_bit_cast(int4, w);
            }
        }
    };

    loadChunk(0);
    writeChunk(0, 0);
    __syncthreads();        // one full (vmcnt) drain for chunk 0
    loadChunk(1);           // chunk 1 flies during chunk 0's 16 steps

    float cstA = 0.0f, cstB = 0.0f;
    float hlastA = 0.0f, hlastB = 0.0f;
    const f32x4 zz = {0.0f, 0.0f, 0.0f, 0.0f};
    f32x4 axA, axB;
    const int4* xsv = reinterpret_cast<const int4*>(xs);
    const int4* hbv = reinterpret_cast<const int4*>(hb);  // 256 int4 per buf

// x-projection (hi+lo weights) for timestep frag pair (X0, X1) -> axA/axB
#define XPROJ(X0, X1)                                                         \
    {                                                                         \
        axA = __builtin_amdgcn_mfma_f32_16x16x32_bf16(wxhA[0], (X0), zz, 0, 0, 0);  \
        axA = __builtin_amdgcn_mfma_f32_16x16x32_bf16(wxhA[1], (X1), axA, 0, 0, 0); \
        axA = __builtin_amdgcn_mfma_f32_16x16x32_bf16(wxlA[0], (X0), axA, 0, 0, 0); \
        axA = __builtin_amdgcn_mfma_f32_16x16x32_bf16(wxlA[1], (X1), axA, 0, 0, 0); \
        axB = __builtin_amdgcn_mfma_f32_16x16x32_bf16(wxhB[0], (X0), zz, 0, 0, 0);  \
        axB = __builtin_amdgcn_mfma_f32_16x16x32_bf16(wxhB[1], (X1), axB, 0, 0, 0); \
        axB = __builtin_amdgcn_mfma_f32_16x16x32_bf16(wxlB[0], (X0), axB, 0, 0, 0); \
        axB = __builtin_amdgcn_mfma_f32_16x16x32_bf16(wxlB[1], (X1), axB, 0, 0, 0); \
    }

// One LSTM step. CUR/TC literal after unroll. LAST=1: stage next chunk
// instead of projecting next x.
#define STEP(CUR, TC, LAST)                                                   \
    {                                                                         \
        const int4* hc = hbv + (CUR) * 256;                                   \
        const bf16x8 bh0 = __builtin_bit_cast(bf16x8, hc[lane]);              \
        const bf16x8 bh1 = __builtin_bit_cast(bf16x8, hc[64 + lane]);         \
        const bf16x8 bl0 = __builtin_bit_cast(bf16x8, hc[128 + lane]);        \
        const bf16x8 bl1 = __builtin_bit_cast(bf16x8, hc[192 + lane]);        \
        f32x4 aA = __builtin_amdgcn_mfma_f32_16x16x32_bf16(whhA[0], bh0, axA, 0, 0, 0); \
        aA = __builtin_amdgcn_mfma_f32_16x16x32_bf16(whhA[1], bh1, aA, 0, 0, 0);        \
        aA = __builtin_amdgcn_mfma_f32_16x16x32_bf16(whhA[0], bl0, aA, 0, 0, 0);        \
        aA = __builtin_amdgcn_mfma_f32_16x16x32_bf16(whhA[1], bl1, aA, 0, 0, 0);        \
        aA = __builtin_amdgcn_mfma_f32_16x16x32_bf16(whlA[0], bh0, aA, 0, 0, 0);        \
        aA = __builtin_amdgcn_mfma_f32_16x16x32_bf16(whlA[1], bh1, aA, 0, 0, 0);        \
        f32x4 aB = __builtin_amdgcn_mfma_f32_16x16x32_bf16(whhB[0], bh0, axB, 0, 0, 0); \
        aB = __builtin_amdgcn_mfma_f32_16x16x32_bf16(whhB[1], bh1, aB, 0, 0, 0);        \
        aB = __builtin_amdgcn_mfma_f32_16x16x32_bf16(whhB[0], bl0, aB, 0, 0, 0);        \
        aB = __builtin_amdgcn_mfma_f32_16x16x32_bf16(whhB[1], bl1, aB, 0, 0, 0);        \
        aB = __builtin_amdgcn_mfma_f32_16x16x32_bf16(whlB[0], bh0, aB, 0, 0, 0);        \
        aB = __builtin_amdgcn_mfma_f32_16x16x32_bf16(whlB[1], bh1, aB, 0, 0, 0);        \
        const float iiA = sigf(aA[0]);                                        \
        const float ffA = sigf(aA[1]);                                        \
        const float g2A = thf(aA[2]);                                         \
        const float ooA = sigf(aA[3]);                                        \
        cstA = fmaf(ffA, cstA, iiA * g2A);                                    \
        const float hA = ooA * thf(cstA);                                     \
        const float iiB = sigf(aB[0]);                                        \
        const float ffB = sigf(aB[1]);                                        \
        const float g2B = thf(aB[2]);                                         \
        const float ooB = sigf(aB[3]);                                        \
        cstB = fmaf(ffB, cstB, iiB * g2B);                                    \
        const float hB = ooB * thf(cstB);                                     \
        const __bf16 hAhi = (__bf16)hA;                                       \
        const __bf16 hBhi = (__bf16)hB;                                       \
        const __bf16 hAlo = (__bf16)(hA - (float)hAhi);                       \
        const __bf16 hBlo = (__bf16)(hB - (float)hBhi);                       \
        unsigned short* hw = hb + ((CUR) ^ 1) * 2048;                         \
        hw[hoffA]        = __builtin_bit_cast(unsigned short, hAhi);          \
        hw[hoffB]        = __builtin_bit_cast(unsigned short, hBhi);          \
        hw[1024 + hoffA] = __builtin_bit_cast(unsigned short, hAlo);          \
        hw[1024 + hoffB] = __builtin_bit_cast(unsigned short, hBlo);          \
        if (!(LAST)) {                                                        \
            const bf16x8 nx0 = __builtin_bit_cast(                            \
                bf16x8, xb[((TC) + 1) * 128 + lane]);                         \
            const bf16x8 nx1 = __builtin_bit_cast(                            \
                bf16x8, xb[((TC) + 1) * 128 + 64 + lane]);                    \
            XPROJ(nx0, nx1);                                                  \
        } else {                                                              \
            writeChunk(c + 1, bb ^ 1);                                        \
            if (c + 2 < NCH) loadChunk(c + 2);                                \
        }                                                                     \
        lgkm_barrier();                                                       \
    }

    for (int c = 0; c < NCH - 1; ++c) {     // 12 full chunks; cur=0 at entry
        const int bb = c & 1;
        const int4* xb = xsv + bb * (CH * 128);

        // x-projection for step 0 of this chunk
        {
            const bf16x8 x0 = __builtin_bit_cast(bf16x8, xb[lane]);
            const bf16x8 x1 = __builtin_bit_cast(bf16x8, xb[64 + lane]);
            XPROJ(x0, x1);
        }
        #pragma unroll
        for (int p = 0; p < 8; ++p) {
            STEP(0, 2 * p, 0);
            STEP(1, 2 * p + 1, (2 * p + 1 == CH - 1));
        }
        // 16 flips -> cur back to 0 at next chunk entry
    }

    // ---- tail chunk (c = 12, L = 1, cur = 0): step t = 192 ----
    {
        const int4* xb = xsv;   // buf 0 (12 & 1 == 0)
        const bf16x8 x0 = __builtin_bit_cast(bf16x8, xb[lane]);
        const bf16x8 x1 = __builtin_bit_cast(bf16x8, xb[64 + lane]);
        XPROJ(x0, x1);

        const bf16x8 bh0 = __builtin_bit_cast(bf16x8, hbv[lane]);
        const bf16x8 bh1 = __builtin_bit_cast(bf16x8, hbv[64 + lane]);
        const bf16x8 bl0 = __builtin_bit_cast(bf16x8, hbv[128 + lane]);
        const bf16x8 bl1 = __builtin_bit_cast(bf16x8, hbv[192 + lane]);
        f32x4 aA = __builtin_amdgcn_mfma_f32_16x16x32_bf16(whhA[0], bh0, axA, 0, 0, 0);
        aA = __builtin_amdgcn_mfma_f32_16x16x32_bf16(whhA[1], bh1, aA, 0, 0, 0);
        aA = __builtin_amdgcn_mfma_f32_16x16x32_bf16(whhA[0], bl0, aA, 0, 0, 0);
        aA = __builtin_amdgcn_mfma_f32_16x16x32_bf16(whhA[1], bl1, aA, 0, 0, 0);
        aA = __builtin_amdgcn_mfma_f32_16x16x32_bf16(whlA[0], bh0, aA, 0, 0, 0);
        aA = __builtin_amdgcn_mfma_f32_16x16x32_bf16(whlA[1], bh1, aA, 0, 0, 0);
        f32x4 aB = __builtin_amdgcn_mfma_f32_16x16x32_bf16(whhB[0], bh0, axB, 0, 0, 0);
        aB = __builtin_amdgcn_mfma_f32_16x16x32_bf16(whhB[1], bh1, aB, 0, 0, 0);
        aB = __builtin_amdgcn_mfma_f32_16x16x32_bf16(whhB[0], bl0, aB, 0, 0, 0);
        aB = __builtin_amdgcn_mfma_f32_16x16x32_bf16(whhB[1], bl1, aB, 0, 0, 0);
        aB = __builtin_amdgcn_mfma_f32_16x16x32_bf16(whlB[0], bh0, aB, 0, 0, 0);
        aB = __builtin_amdgcn_mfma_f32_16x16x32_bf16(whlB[1], bh1, aB, 0, 0, 0);

        cstA = fmaf(sigf(aA[1]), cstA, sigf(aA[0]) * thf(aA[2]));
        hlastA = sigf(aA[3]) * thf(cstA);
        cstB = fmaf(sigf(aB[1]), cstB, sigf(aB[0]) * thf(aB[2]));
        hlastB = sigf(aB[3]) * thf(cstB);
    }

    if (uA < 50) hfin[n * 53 + uA] = hlastA;
    if (uB < 50) hfin[n * 53 + uB] = hlastB;
    __syncthreads();

    // ---- FC head + log_softmax ----
    if (tid < BT * V_) {
        const int bn = tid / V_;
        const int v  = tid % V_;
        float a = fc_b[v];
        #pragma unroll
        for (int j = 0; j < 50; ++j) {
            float hj = hfin[bn * 53 + j];
            hj = hj > 0.0f ? hj : 0.0f;
            a = fmaf(hj, fc_w[v * 50 + j], a);
        }
        lgts[bn][v] = a;
    }
    __syncthreads();
    if (tid < BT * V_) {
        const int bn = tid / V_;
        const int v  = tid % V_;
        float m = -1e30f;
        #pragma unroll
        for (int u = 0; u < V_; ++u) m = fmaxf(m, lgts[bn][u]);
        float s = 0.0f;
        #pragma unroll
        for (int u = 0; u < V_; ++u) s += __expf(lgts[bn][u] - m);
        out[(size_t)(row0 + bn) * V_ + v] = lgts[bn][v] - m - __logf(s);
    }
}

extern "C" void kernel_launch(void* const* d_in, const int* in_sizes, int n_in,
                              void* d_out, int out_size, void* d_ws, size_t ws_size,
                              hipStream_t stream) {
    const float* x    = (const float*)d_in[0];
    const float* W_ih = (const float*)d_in[1];
    const float* W_hh = (const float*)d_in[2];
    const float* b_ih = (const float*)d_in[3];
    const float* b_hh = (const float*)d_in[4];
    const float* fc_w = (const float*)d_in[5];
    const float* fc_b = (const float*)d_in[6];
    float* out = (float*)d_out;

    lstm_mfma_kernel<<<NBLK, NTHREADS, 0, stream>>>(
        x, W_ih, W_hh, b_ih, b_hh, fc_w, fc_b, out);
}